// Round 1
// baseline (72.738 us; speedup 1.0000x reference)
//
#include <hip/hip_runtime.h>
#include <math.h>

constexpr int PAD = 0;
constexpr int Lc = 128;   // sequence length
constexpr int Dc = 128;   // embedding dim
constexpr float MIN_NORM = 1e-15f;
constexpr float CLAMP_ABS_EPS = 1e-10f;
constexpr float ATANH_EPS = 1e-7f;

__device__ __forceinline__ float red32(float v) {
    // reduce across each 32-lane half of the wave (xor masks < 32 stay in-half)
    v += __shfl_xor(v, 16);
    v += __shfl_xor(v, 8);
    v += __shfl_xor(v, 4);
    v += __shfl_xor(v, 2);
    v += __shfl_xor(v, 1);
    return v;
}

__device__ __forceinline__ float red64(float v) {
    v += __shfl_xor(v, 32);
    return red32(v);
}

__global__ __launch_bounds__(256) void hyper_enc_kernel(
        const int* __restrict__ padded,
        const float* __restrict__ emb,
        float* __restrict__ out) {
    const int b    = blockIdx.x;
    const int tid  = threadIdx.x;
    const int wave = tid >> 6;
    const int lane = tid & 63;
    const int half = lane >> 5;   // which token of the pair
    const int l32  = lane & 31;   // dim-group within token

    __shared__ int   sidx[Lc];
    __shared__ float s_num[8][Dc];   // per (wave,half) partial nominators
    __shared__ float s_den[8];
    __shared__ int   s_cnt;
    __shared__ float s_sd;
    __shared__ float s_red[4];

    // ---- stage indices, count non-pad tokens ----
    int myidx = 0;
    if (tid < Lc) { myidx = padded[(size_t)b * Lc + tid]; sidx[tid] = myidx; }
    if (tid == 0) s_cnt = 0;
    __syncthreads();
    if (tid < Lc) {  // waves 0,1 fully active -> ballot is wave-uniform
        unsigned long long bal = __ballot(myidx != PAD);
        if (lane == 0) atomicAdd(&s_cnt, (int)__popcll(bal));
    }
    __syncthreads();

    // ---- main gather + accumulate: 2 tokens per wave-iteration, float4 loads ----
    float4 snum = make_float4(0.f, 0.f, 0.f, 0.f);
    float  sden = 0.f;
    const int lbase = wave * 32 + half;
    #pragma unroll 4
    for (int j = 0; j < 16; ++j) {
        const int l   = lbase + 2 * j;
        const int idx = sidx[l];
        const float4 z = *reinterpret_cast<const float4*>(emb + (size_t)idx * Dc + l32 * 4);
        float p = z.x * z.x + z.y * z.y;
        p += z.z * z.z;
        p += z.w * z.w;
        const float n2  = red32(p);                         // ||z_l||^2
        const float lam = 2.0f / fmaxf(1.0f - n2, MIN_NORM);
        const bool  act = (idx != PAD);
        const float wl  = act ? lam : 0.0f;
        sden += act ? (lam - 1.0f) : 0.0f;
        snum.x = fmaf(wl, z.x, snum.x);
        snum.y = fmaf(wl, z.y, snum.y);
        snum.z = fmaf(wl, z.z, snum.z);
        snum.w = fmaf(wl, z.w, snum.w);
    }
    const int g = wave * 2 + half;
    *reinterpret_cast<float4*>(&s_num[g][l32 * 4]) = snum;
    if (l32 == 0) s_den[g] = sden;
    __syncthreads();

    // ---- combine 8 partial groups ----
    float nom = 0.f;
    if (tid < Dc) {
        #pragma unroll
        for (int gg = 0; gg < 8; ++gg) nom += s_num[gg][tid];
    }
    if (tid == 0) {
        float t = 0.f;
        #pragma unroll
        for (int gg = 0; gg < 8; ++gg) t += s_den[gg];
        s_sd = t;
    }
    __syncthreads();

    const int cnt = s_cnt;
    if (cnt == 0) {  // all-pad row -> zeros (uniform branch, safe to return)
        for (int i = tid; i < 4 * Dc; i += 256)
            out[(size_t)b * (4 * Dc) + i] = 0.f;
        return;
    }
    const float Sd = s_sd;

    // ---- two_mean (all four scales reduce to the same uniform weights 1/cnt) ----
    float tm = 0.f;
    if (tid < Dc) {
        const float rc    = 1.0f / (float)cnt;
        const float dn    = Sd * rc;
        const float denom = ((dn >= 0.f) ? 1.0f : -1.0f) * fmaxf(fabsf(dn), CLAMP_ABS_EPS);
        tm = (nom * rc) / denom;
    }

    // ---- ||two_mean|| : block reduce over waves 0,1 (others contribute 0) ----
    float p2 = red64(tm * tm);
    if (lane == 0) s_red[wave] = p2;
    __syncthreads();
    const float n2sum = s_red[0] + s_red[1];
    const float n2 = fmaxf(sqrtf(n2sum), MIN_NORM);
    const float xc = fminf(n2, 1.0f - ATANH_EPS);
    // tanh(0.5 * artanh(x)) == x / (1 + sqrt(1 - x^2))
    const float t_half = xc / (1.0f + sqrtf(fmaxf(1.0f - xc * xc, 0.f)));
    const float mid = tm * (t_half / n2);

    // ---- ||mid|| ----
    __syncthreads();   // protect s_red reuse
    float q2 = red64(mid * mid);
    if (lane == 0) s_red[wave] = q2;
    __syncthreads();
    const float nmsum = s_red[0] + s_red[1];
    const float nm  = fmaxf(sqrtf(nmsum), MIN_NORM);
    const float xc2 = fminf(nm, 1.0f - ATANH_EPS);
    const float f   = 0.5f * logf((1.0f + xc2) / (1.0f - xc2));   // artanh

    // ---- logmap0 + replicate across the 4 scales ----
    if (tid < Dc) {
        const float o = mid * (f / nm);
        float* orow = out + (size_t)b * (4 * Dc);
        orow[0 * Dc + tid] = o;
        orow[1 * Dc + tid] = o;
        orow[2 * Dc + tid] = o;
        orow[3 * Dc + tid] = o;
    }
}

extern "C" void kernel_launch(void* const* d_in, const int* in_sizes, int n_in,
                              void* d_out, int out_size, void* d_ws, size_t ws_size,
                              hipStream_t stream) {
    const int*   padded = (const int*)d_in[0];
    const float* emb    = (const float*)d_in[1];
    float*       out    = (float*)d_out;
    const int Bn = in_sizes[0] / Lc;   // 8192
    hyper_enc_kernel<<<Bn, 256, 0, stream>>>(padded, emb, out);
}